// Round 9
// baseline (676.219 us; speedup 1.0000x reference)
//
#include <hip/hip_runtime.h>
#include <math.h>

#define Bb 8
#define Ss 2048
#define Ee 256
#define Hh 4
#define Dd 64

typedef unsigned short u16;
typedef unsigned int u32;
typedef __attribute__((ext_vector_type(8))) short bf16x8;
typedef __attribute__((ext_vector_type(4))) float f32x4;

__device__ __forceinline__ u16 f2bf(float f) {
  union { float f; u32 u; } c; c.f = f;
  return (u16)((c.u + 0x7FFFu + ((c.u >> 16) & 1u)) >> 16);
}
__device__ __forceinline__ float bf2f(u16 u) {
  union { u32 u; float f; } c; c.u = ((u32)u) << 16;
  return c.f;
}
__device__ __forceinline__ float bf2fs(short s) { return bf2f((u16)s); }

// ---------------- weight fp32 -> bf16 convert ----------------
__global__ __launch_bounds__(256) void k_w2b(const float* __restrict__ src,
                                             u16* __restrict__ dst) {
  int idx = (blockIdx.x * 256 + threadIdx.x) * 4;
  float4 v = *reinterpret_cast<const float4*>(src + idx);
  ushort4 o;
  o.x = f2bf(v.x); o.y = f2bf(v.y); o.z = f2bf(v.z); o.w = f2bf(v.w);
  *reinterpret_cast<ushort4*>(dst + idx) = o;
}

// ---------------- embedding gather (fp32 x + bf16 xb) ----------------
__global__ __launch_bounds__(256) void k_gather(const int* __restrict__ seqs,
                                                const float* __restrict__ emb,
                                                float* __restrict__ x,
                                                u16* __restrict__ xb) {
  int idx = blockIdx.x * 256 + threadIdx.x;
  int row = idx >> 6, c4 = idx & 63;
  int tok = seqs[row];
  float4 v = reinterpret_cast<const float4*>(emb)[(size_t)tok * 64 + c4];
  reinterpret_cast<float4*>(x)[(size_t)row * 64 + c4] = v;
  ushort4 o;
  o.x = f2bf(v.x); o.y = f2bf(v.y); o.z = f2bf(v.z); o.w = f2bf(v.w);
  reinterpret_cast<ushort4*>(xb)[(size_t)row * 64 + c4] = o;
}

// ---------------- QKV projection (MFMA bf16): relu(xb@W^T+b) -> bf16 --------
// Q output pre-scaled by 1/16 (folds the attention scale into Qf).
__global__ __launch_bounds__(256) void k_qkvm(const u16* __restrict__ xb,
    const u16* __restrict__ Wqb, const u16* __restrict__ Wkb, const u16* __restrict__ Wvb,
    const float* __restrict__ bq, const float* __restrict__ bk, const float* __restrict__ bv,
    u16* __restrict__ Qf, u16* __restrict__ Kf, u16* __restrict__ Vf, int mod) {
  __shared__ short Xs[128][72];
  __shared__ short Ws[128][72];
  int tid = threadIdx.x;
  int bn = blockIdx.x;
  int arr = bn >> 1, coff = (bn & 1) << 7;
  const u16* W = (arr == 0 ? Wqb : arr == 1 ? Wkb : Wvb) + (size_t)mod * 256 * 256;
  const float* bias = (arr == 0 ? bq : arr == 1 ? bk : bv) + mod * 256;
  u16* Out = (arr == 0 ? Qf : arr == 1 ? Kf : Vf);
  float oscale = (arr == 0) ? 0.0625f : 1.0f;
  int s0 = blockIdx.y * 128;
  int lr = tid >> 1, lc = (tid & 1) << 5;
  int w = tid >> 6, lane = tid & 63, ml = lane & 15, q = lane >> 4;
  int sh = (w >> 1) << 6, th = (w & 1) << 6;
  f32x4 acc[4][4] = {};
  for (int k0 = 0; k0 < 256; k0 += 64) {
#pragma unroll
    for (int hh = 0; hh < 4; hh++) {
      *reinterpret_cast<bf16x8*>(&Xs[lr][lc + hh * 8]) =
          *reinterpret_cast<const bf16x8*>(xb + (size_t)(s0 + lr) * Ee + k0 + lc + hh * 8);
      *reinterpret_cast<bf16x8*>(&Ws[lr][lc + hh * 8]) =
          *reinterpret_cast<const bf16x8*>(W + (size_t)(coff + lr) * Ee + k0 + lc + hh * 8);
    }
    __syncthreads();
#pragma unroll
    for (int ks = 0; ks < 2; ks++) {
      bf16x8 af[4], bfr[4];
#pragma unroll
      for (int mt = 0; mt < 4; mt++)
        af[mt] = *reinterpret_cast<const bf16x8*>(&Xs[sh + mt * 16 + ml][ks * 32 + q * 8]);
#pragma unroll
      for (int nt = 0; nt < 4; nt++)
        bfr[nt] = *reinterpret_cast<const bf16x8*>(&Ws[th + nt * 16 + ml][ks * 32 + q * 8]);
#pragma unroll
      for (int mt = 0; mt < 4; mt++)
#pragma unroll
        for (int nt = 0; nt < 4; nt++)
          acc[mt][nt] = __builtin_amdgcn_mfma_f32_16x16x32_bf16(af[mt], bfr[nt], acc[mt][nt], 0, 0, 0);
    }
    __syncthreads();
  }
#pragma unroll
  for (int mt = 0; mt < 4; mt++)
#pragma unroll
    for (int nt = 0; nt < 4; nt++)
#pragma unroll
      for (int r = 0; r < 4; r++) {
        int gm = s0 + sh + mt * 16 + q * 4 + r;
        int cc = coff + th + nt * 16 + ml;
        float v = acc[mt][nt][r] + bias[cc];
        v = (v > 0.f ? v : 0.f) * oscale;
        Out[(size_t)gm * Ee + cc] = f2bf(v);
      }
}

// ---------------- V transpose: Vf[b][t][h*64+d] -> Vt[(b*4+h)*64+d][t] -------
__global__ __launch_bounds__(256) void k_vt(const u16* __restrict__ Vf,
                                            u16* __restrict__ Vt) {
  __shared__ u16 T[64][72];
  int tid = threadIdx.x;
  int t0 = blockIdx.x * 64;
  int z = blockIdx.y;
  int b = z >> 2, h = z & 3;
  int lr = tid >> 2, lc = (tid & 3) << 4;
#pragma unroll
  for (int hh = 0; hh < 2; hh++) {
    bf16x8 v = *reinterpret_cast<const bf16x8*>(
        Vf + (size_t)(b * Ss + t0 + lr) * Ee + h * Dd + lc + hh * 8);
#pragma unroll
    for (int j = 0; j < 8; j++) T[lr][lc + hh * 8 + j] = (u16)v[j];
  }
  __syncthreads();
#pragma unroll
  for (int j = 0; j < 16; j++) {
    Vt[((size_t)z * Dd + lr) * Ss + t0 + lc + j] = T[lc + j][lr];
  }
}

// ---------------- SV[z][d] = sum_t Vt[z*64+d][t] -----------------------------
__global__ __launch_bounds__(256) void k_vsum(const u16* __restrict__ Vt,
                                              float* __restrict__ SV) {
  int z = blockIdx.y;
  int d = blockIdx.x * 4 + (threadIdx.x >> 6);
  int lane = threadIdx.x & 63;
  const u16* row = Vt + ((size_t)z * Dd + d) * Ss;
  float s = 0.f;
#pragma unroll
  for (int it = 0; it < 4; it++) {
    bf16x8 v = *reinterpret_cast<const bf16x8*>(row + it * 512 + lane * 8);
#pragma unroll
    for (int j = 0; j < 8; j++) s += bf2fs(v[j]);
  }
#pragma unroll
  for (int off = 32; off; off >>= 1) s += __shfl_xor(s, off);
  if (lane == 0) SV[(size_t)z * Dd + d] = s;
}

// ---------------- pass 1: llic[t] = -ln(sum_s exp(S)) --------------------------
// grid (32 t-tiles of 64, 32 z). Each wave owns 16 t-cols (K-frags in regs);
// Q double-buffered in LDS -> 1 barrier/iter. No cross-wave combine needed.
__global__ __launch_bounds__(256) void k_csum(const u16* __restrict__ Qf,
    const u16* __restrict__ Kf, float* __restrict__ llic) {
  __shared__ short Qs[2][128 * 68];
  int tid = threadIdx.x;
  int z = blockIdx.y, b = z >> 2, h = z & 3;
  const u16* Qb = Qf + (size_t)b * Ss * Ee + h * Dd;
  const u16* Kb = Kf + (size_t)b * Ss * Ee + h * Dd;
  int t0 = blockIdx.x * 64;
  int lr = tid >> 1, lc = (tid & 1) << 5;
  int w = tid >> 6, lane = tid & 63, ml = lane & 15, q = lane >> 4;
  // wave's 16 K columns in registers (loop-invariant)
  bf16x8 kb[2];
#pragma unroll
  for (int ks = 0; ks < 2; ks++)
    kb[ks] = *reinterpret_cast<const bf16x8*>(
        Kb + (size_t)(t0 + w * 16 + ml) * Ee + ks * 32 + q * 8);
  // prologue: stage rows 0..127 into buf 0
#pragma unroll
  for (int hh = 0; hh < 4; hh++)
    *reinterpret_cast<bf16x8*>(&Qs[0][lr * 68 + lc + hh * 8]) =
        *reinterpret_cast<const bf16x8*>(Qb + (size_t)lr * Ee + lc + hh * 8);
  float csum = 0.f;
  for (int i = 0; i < 16; i++) {
    __syncthreads();
    if (i + 1 < 16) {
#pragma unroll
      for (int hh = 0; hh < 4; hh++)
        *reinterpret_cast<bf16x8*>(&Qs[(i + 1) & 1][lr * 68 + lc + hh * 8]) =
            *reinterpret_cast<const bf16x8*>(
                Qb + (size_t)((i + 1) * 128 + lr) * Ee + lc + hh * 8);
    }
    const short* Qcur = Qs[i & 1];
#pragma unroll
    for (int mt = 0; mt < 8; mt++) {
      f32x4 acc = {};
#pragma unroll
      for (int ks = 0; ks < 2; ks++) {
        bf16x8 af = *reinterpret_cast<const bf16x8*>(
            &Qcur[(mt * 16 + ml) * 68 + ks * 32 + q * 8]);
        acc = __builtin_amdgcn_mfma_f32_16x16x32_bf16(af, kb[ks], acc, 0, 0, 0);
      }
#pragma unroll
      for (int r = 0; r < 4; r++) csum += __expf(acc[r]);
    }
  }
  // reduce over the 4 q-row-groups (same column ml)
  csum += __shfl_xor(csum, 16);
  csum += __shfl_xor(csum, 32);
  if (lane < 16)
    llic[(size_t)z * Ss + t0 + w * 16 + ml] = -__logf(csum);
}

// ---------------- pass 2: fused attention, 64-row s-tiles --------------------
// grid (32 s-tiles, 32 z), 4 waves/block. Wave owns 16 s-rows end-to-end:
// QK-MFMA (regs Q) -> e1=exp(S+llic) -> A2'=expm1-poly -> wave-private A2s
// (no barrier) -> PV-MFMA. O = (SV + A2'@V)/(2048+rowsum) -> bf16 Zb.
__global__ __launch_bounds__(256) void k_att(const u16* __restrict__ Qf,
    const u16* __restrict__ Kf, const u16* __restrict__ Vt,
    const float* __restrict__ llic, const float* __restrict__ SV,
    u16* __restrict__ Zb) {
  __shared__ short Ks[64 * 68];      // 8.7 KB
  __shared__ short Vs[64 * 68];      // 8.7 KB
  __shared__ short A2s[64 * 76];     // 9.7 KB (wave-private 16-row slices)
  int tid = threadIdx.x;
  int z = blockIdx.y, b = z >> 2, h = z & 3;
  const u16* Qb = Qf + (size_t)b * Ss * Ee + h * Dd;
  const u16* Kb = Kf + (size_t)b * Ss * Ee + h * Dd;
  const u16* VtZ = Vt + (size_t)z * Dd * Ss;
  const float* lz = llic + (size_t)z * Ss;
  int s0 = blockIdx.x * 64;
  int w = tid >> 6, lane = tid & 63, ml = lane & 15, q = lane >> 4;
  // Q A-frags for this wave's 16 rows (loop-invariant)
  bf16x8 qa[2];
#pragma unroll
  for (int ks = 0; ks < 2; ks++)
    qa[ks] = *reinterpret_cast<const bf16x8*>(
        Qb + (size_t)(s0 + w * 16 + ml) * Ee + ks * 32 + q * 8);
  f32x4 acc2[4] = {};
  float rsv[4] = {};
  for (int t0 = 0; t0 < Ss; t0 += 64) {
    __syncthreads();
    if (tid < 128) {
      int r2 = tid >> 1, h2 = (tid & 1) << 5;
#pragma unroll
      for (int j = 0; j < 4; j++)
        *reinterpret_cast<bf16x8*>(&Ks[r2 * 68 + h2 + j * 8]) =
            *reinterpret_cast<const bf16x8*>(Kb + (size_t)(t0 + r2) * Ee + h2 + j * 8);
    } else {
      int t2 = tid - 128;
      int r2 = t2 >> 1, h2 = (t2 & 1) << 5;
#pragma unroll
      for (int j = 0; j < 4; j++)
        *reinterpret_cast<bf16x8*>(&Vs[r2 * 68 + h2 + j * 8]) =
            *reinterpret_cast<const bf16x8*>(VtZ + (size_t)r2 * Ss + t0 + h2 + j * 8);
    }
    __syncthreads();
    // QK: wave's 16 s-rows x 64 t-cols
    f32x4 acc[4] = {};
#pragma unroll
    for (int ks = 0; ks < 2; ks++) {
      bf16x8 bf[4];
#pragma unroll
      for (int nt = 0; nt < 4; nt++)
        bf[nt] = *reinterpret_cast<const bf16x8*>(&Ks[(nt * 16 + ml) * 68 + ks * 32 + q * 8]);
#pragma unroll
      for (int nt = 0; nt < 4; nt++)
        acc[nt] = __builtin_amdgcn_mfma_f32_16x16x32_bf16(qa[ks], bf[nt], acc[nt], 0, 0, 0);
    }
    // transform (wave-private A2s rows -> no barrier before PV)
#pragma unroll
    for (int nt = 0; nt < 4; nt++) {
      float lcv = lz[t0 + nt * 16 + ml];
#pragma unroll
      for (int r = 0; r < 4; r++) {
        float e1 = __expf(acc[nt][r] + lcv);
        float p = e1 * (1.f + e1 * (0.5f + e1 * (0.166666667f + e1 * 0.0416666667f)));
        rsv[r] += p;
        union { float f; u32 u; } cv; cv.f = p;
        A2s[(w * 16 + q * 4 + r) * 76 + nt * 16 + ml] = (short)((cv.u + 0x8000u) >> 16);
      }
    }
    // PV: wave's 16 s-rows x 64 d
#pragma unroll
    for (int ks = 0; ks < 2; ks++) {
      bf16x8 af = *reinterpret_cast<const bf16x8*>(
          &A2s[(w * 16 + ml) * 76 + ks * 32 + q * 8]);
#pragma unroll
      for (int nt = 0; nt < 4; nt++) {
        bf16x8 bv = *reinterpret_cast<const bf16x8*>(&Vs[(nt * 16 + ml) * 68 + ks * 32 + q * 8]);
        acc2[nt] = __builtin_amdgcn_mfma_f32_16x16x32_bf16(af, bv, acc2[nt], 0, 0, 0);
      }
    }
  }
  // rowsum butterfly over ml bits (rows are wave-private)
#pragma unroll
  for (int r = 0; r < 4; r++) {
    float v = rsv[r];
    v += __shfl_xor(v, 1); v += __shfl_xor(v, 2);
    v += __shfl_xor(v, 4); v += __shfl_xor(v, 8);
    rsv[r] = v;
  }
  const float* SVz = SV + (size_t)z * Dd;
#pragma unroll
  for (int r = 0; r < 4; r++) {
    int row = s0 + w * 16 + q * 4 + r;
    float inv = 1.f / (2048.f + rsv[r]);
#pragma unroll
    for (int nt = 0; nt < 4; nt++) {
      float o = (SVz[nt * 16 + ml] + acc2[nt][r]) * inv;
      Zb[(size_t)(b * Ss + row) * Ee + h * Dd + nt * 16 + ml] = f2bf(o);
    }
  }
}

// ---------------- ZF (MFMA bf16) + residual: x += Zb@Wz^T + bz; xb refresh ---
__global__ __launch_bounds__(256) void k_zfm(const u16* __restrict__ Zb,
    const u16* __restrict__ Wzb, const float* __restrict__ bzp,
    float* __restrict__ x, u16* __restrict__ xb, int mod) {
  __shared__ short Zs[128][72];
  __shared__ short Ws[128][72];
  int tid = threadIdx.x;
  int coff = blockIdx.x << 7;
  const u16* W = Wzb + (size_t)mod * 256 * 256;
  const float* bias = bzp + mod * Ee;
  int s0 = blockIdx.y * 128;
  int lr = tid >> 1, lc = (tid & 1) << 5;
  int w = tid >> 6, lane = tid & 63, ml = lane & 15, q = lane >> 4;
  int sh = (w >> 1) << 6, th = (w & 1) << 6;
  f32x4 acc[4][4] = {};
  for (int k0 = 0; k0 < 256; k0 += 64) {
#pragma unroll
    for (int hh = 0; hh < 4; hh++) {
      *reinterpret_cast<bf16x8*>(&Zs[lr][lc + hh * 8]) =
          *reinterpret_cast<const bf16x8*>(Zb + (size_t)(s0 + lr) * Ee + k0 + lc + hh * 8);
      *reinterpret_cast<bf16x8*>(&Ws[lr][lc + hh * 8]) =
          *reinterpret_cast<const bf16x8*>(W + (size_t)(coff + lr) * Ee + k0 + lc + hh * 8);
    }
    __syncthreads();
#pragma unroll
    for (int ks = 0; ks < 2; ks++) {
      bf16x8 af[4], bfr[4];
#pragma unroll
      for (int mt = 0; mt < 4; mt++)
        af[mt] = *reinterpret_cast<const bf16x8*>(&Zs[sh + mt * 16 + ml][ks * 32 + q * 8]);
#pragma unroll
      for (int nt = 0; nt < 4; nt++)
        bfr[nt] = *reinterpret_cast<const bf16x8*>(&Ws[th + nt * 16 + ml][ks * 32 + q * 8]);
#pragma unroll
      for (int mt = 0; mt < 4; mt++)
#pragma unroll
        for (int nt = 0; nt < 4; nt++)
          acc[mt][nt] = __builtin_amdgcn_mfma_f32_16x16x32_bf16(af[mt], bfr[nt], acc[mt][nt], 0, 0, 0);
    }
    __syncthreads();
  }
#pragma unroll
  for (int mt = 0; mt < 4; mt++)
#pragma unroll
    for (int nt = 0; nt < 4; nt++)
#pragma unroll
      for (int r = 0; r < 4; r++) {
        int gm = s0 + sh + mt * 16 + q * 4 + r;
        int gn = coff + th + nt * 16 + ml;
        float xv = x[(size_t)gm * Ee + gn] + acc[mt][nt][r] + bias[gn];
        x[(size_t)gm * Ee + gn] = xv;
        xb[(size_t)gm * Ee + gn] = f2bf(xv);
      }
}

// ---------------- final head ----------------
__global__ __launch_bounds__(256) void k_final1(const float* __restrict__ x,
    const float* __restrict__ Wo, float* __restrict__ part) {
  int c = blockIdx.x, l = blockIdx.y, b = blockIdx.z;
  int tid = threadIdx.x;
  const float4* xr = reinterpret_cast<const float4*>(x + (size_t)b * (Ss * Ee) + c * 8192);
  const float4* wr = reinterpret_cast<const float4*>(Wo + (size_t)l * (Ss * Ee) + c * 8192);
  float sum = 0.f;
  for (int i = tid; i < 2048; i += 256) {
    float4 a = xr[i], w = wr[i];
    sum += a.x * w.x + a.y * w.y + a.z * w.z + a.w * w.w;
  }
  __shared__ float red[256];
  red[tid] = sum;
  __syncthreads();
  for (int o = 128; o; o >>= 1) {
    if (tid < o) red[tid] += red[tid + o];
    __syncthreads();
  }
  if (tid == 0) part[((b * 16 + l) << 6) + c] = red[0];
}

__global__ void k_final2(const float* __restrict__ part, const float* __restrict__ bo,
                         float* __restrict__ out) {
  int idx = threadIdx.x;   // 128 = 8*16
  int b = idx >> 4, l = idx & 15;
  float s = 0.f;
  for (int c = 0; c < 64; c++) s += part[((b * 16 + l) << 6) + c];
  s += bo[l];
  out[idx] = 1.f / (1.f + __expf(-s));
}

extern "C" void kernel_launch(void* const* d_in, const int* in_sizes, int n_in,
                              void* d_out, int out_size, void* d_ws, size_t ws_size,
                              hipStream_t stream) {
  const int*   seqs = (const int*)d_in[0];
  const float* emb  = (const float*)d_in[1];
  const float* Wq   = (const float*)d_in[2];
  const float* bq   = (const float*)d_in[3];
  const float* Wk   = (const float*)d_in[4];
  const float* bk   = (const float*)d_in[5];
  const float* Wv   = (const float*)d_in[6];
  const float* bv   = (const float*)d_in[7];
  const float* Wz   = (const float*)d_in[8];
  const float* bz   = (const float*)d_in[9];
  const float* Wo   = (const float*)d_in[10];
  const float* bo   = (const float*)d_in[11];
  float* out = (float*)d_out;
  float* ws  = (float*)d_ws;

  float* x    = ws;                                    // 4,194,304 f
  u16*   xb   = (u16*)(ws + 4194304);
  u16*   Qf   = (u16*)(ws + 6291456);
  u16*   Kf   = (u16*)(ws + 8388608);
  u16*   Vf   = (u16*)(ws + 10485760);
  u16*   Vt   = (u16*)(ws + 12582912);
  u16*   Zb   = (u16*)(ws + 14680064);
  float* SV   = ws + 16777216;                         // 2,048 f
  float* part = ws + 16779264;                         // 8,192 f
  u16*   Wqb  = (u16*)(ws + 16787456);
  u16*   Wkb  = (u16*)(ws + 16852992);
  u16*   Wvb  = (u16*)(ws + 16918528);
  u16*   Wzb  = (u16*)(ws + 16984064);
  float* llic = ws + 17049600;                         // 65,536 f (32 z x 2048)

  k_gather<<<(Bb * Ss * 64) / 256, 256, 0, stream>>>(seqs, emb, x, xb);
  k_w2b<<<131072 / 1024, 256, 0, stream>>>(Wq, Wqb);
  k_w2b<<<131072 / 1024, 256, 0, stream>>>(Wk, Wkb);
  k_w2b<<<131072 / 1024, 256, 0, stream>>>(Wv, Wvb);
  k_w2b<<<131072 / 1024, 256, 0, stream>>>(Wz, Wzb);

  for (int m = 0; m < 2; m++) {
    k_qkvm<<<dim3(6, 128), 256, 0, stream>>>(xb, Wqb, Wkb, Wvb, bq, bk, bv, Qf, Kf, Vf, m);
    k_vt<<<dim3(32, 32), 256, 0, stream>>>(Vf, Vt);
    k_vsum<<<dim3(16, 32), 256, 0, stream>>>(Vt, SV);
    k_csum<<<dim3(32, 32), 256, 0, stream>>>(Qf, Kf, llic);
    k_att<<<dim3(32, 32), 256, 0, stream>>>(Qf, Kf, Vt, llic, SV, Zb);
    k_zfm<<<dim3(2, 128), 256, 0, stream>>>(Zb, Wzb, bz, x, xb, m);
  }

  k_final1<<<dim3(64, 16, 8), 256, 0, stream>>>(x, Wo, part);
  k_final2<<<1, 128, 0, stream>>>(part, bo, out);
}